// Round 11
// baseline (5196.692 us; speedup 1.0000x reference)
//
#include <hip/hip_runtime.h>

#define LOG2E 1.4426950408889634f

__device__ __forceinline__ unsigned short f2bf(float f) {
  unsigned u = __float_as_uint(f);
  u += 0x7FFFu + ((u >> 16) & 1u);            // round-to-nearest-even
  return (unsigned short)(u >> 16);
}
__device__ __forceinline__ unsigned pk2(float a, float b) {
  return (unsigned)f2bf(a) | ((unsigned)f2bf(b) << 16);
}
__device__ __forceinline__ float bl16(unsigned u) { return __uint_as_float(u << 16); }
__device__ __forceinline__ float bh16(unsigned u) { return __uint_as_float(u & 0xFFFF0000u); }

// LDS-visibility barrier WITHOUT the vmcnt(0) drain __syncthreads would emit.
__device__ __forceinline__ void lds_barrier() {
  asm volatile("s_waitcnt lgkmcnt(0)" ::: "memory");
  __builtin_amdgcn_s_barrier();
}

// DPP cross-lane adds (VALU pipe): reduce over 8 consecutive lanes.
__device__ __forceinline__ float dpp_xor1_add(float x) {
  return x + __int_as_float(__builtin_amdgcn_update_dpp(
      0, __float_as_int(x), 0xB1, 0xF, 0xF, true));
}
__device__ __forceinline__ float dpp_xor2_add(float x) {
  return x + __int_as_float(__builtin_amdgcn_update_dpp(
      0, __float_as_int(x), 0x4E, 0xF, 0xF, true));
}
__device__ __forceinline__ float dpp_xor7_add(float x) {
  return x + __int_as_float(__builtin_amdgcn_update_dpp(
      0, __float_as_int(x), 0x141, 0xF, 0xF, true));
}
__device__ __forceinline__ float red8(float x) {
  x = dpp_xor1_add(x);
  x = dpp_xor2_add(x);
  x = dpp_xor7_add(x);
  return x;
}

// ---------------- prep: fold constants, softplus; emit swizzled {c2,a2} image + we ----------------
__global__ __launch_bounds__(256) void prep_kernel(
    const float* __restrict__ sigma, const float* __restrict__ mu,
    const float* __restrict__ w,     const float* __restrict__ erev,
    const float* __restrict__ ss,    const float* __restrict__ smu,
    const float* __restrict__ sw,    const float* __restrict__ serev,
    const float* __restrict__ iw,    const float* __restrict__ ib,
    const float* __restrict__ gleak, const float* __restrict__ vleak,
    const float* __restrict__ cm,
    float2* __restrict__ Pimg, float* __restrict__ WEr,
    float* __restrict__ C2s, float* __restrict__ A2s, float* __restrict__ WEs,
    float* __restrict__ vecs)
{
  int gid = blockIdx.x * 256 + threadIdx.x;
  if (gid < 16384) {
    int i = gid >> 7, j = gid & 127;
    float a2 = sigma[gid] * LOG2E;
    float c2 = a2 * mu[gid];
    float sp = log1pf(expf(w[gid]));          // softplus(w) > 0
    float we = sp * erev[gid];                // erev = +-1
    // swizzled LDS image: thread (j, iq=i>>4) reads pair c=(i&15)>>1 at
    // byte j*1024 + iq*128 + ((c ^ (j&7))<<4) -> balanced-bank ds_read_b128
    int iq = i >> 4, k = i & 15, c = k >> 1, h = k & 1, jj = j & 7;
    int idx8 = j * 128 + iq * 16 + ((c ^ jj) << 1) + h;
    Pimg[idx8] = make_float2(c2, a2);
    WEr[j * 128 + i] = we;                    // [j][i], consecutive per thread
  } else if (gid < 32768) {
    int e = gid - 16384;
    int i = e >> 7, j = e & 127;
    int idx = j * 128 + i;
    float a2 = ss[e] * iw[i] * LOG2E;         // fold input_w
    float c2 = ss[e] * (smu[e] - ib[i]) * LOG2E; // fold input_b
    float sp = log1pf(expf(sw[e]));
    float we = sp * serev[e];
    C2s[idx] = c2; A2s[idx] = a2; WEs[idx] = we;
  } else if (gid < 32896) {
    int jj = gid - 32768;
    float gp = log1pf(expf(gleak[jj]));
    vecs[jj]       = log1pf(expf(cm[jj])) * 4.0f; // cm_t = softplus(cm)*ODE_UNFOLDS
    vecs[128 + jj] = gp;                          // gleak_p
    vecs[256 + jj] = gp * vleak[jj];              // gleak_p * vleak
  }
}

// ---------------- stage A: h = LN(x @ W^T + b), write bf16 (unchanged, known-good) ----------------
__global__ __launch_bounds__(256) void stage_a(
    const float* __restrict__ x, const float* __restrict__ W,
    const float* __restrict__ pb, const float* __restrict__ lg,
    const float* __restrict__ lb, uint4* __restrict__ hout)
{
  extern __shared__ char smem[];
  float* Wt = (float*)smem;            // [128][132] transposed W (k-major), padded
  float* xs = Wt + 128 * 132;          // [32][132]
  const int tid = threadIdx.x;

  #pragma unroll
  for (int ii = 0; ii < 16; ++ii) {
    int f = tid + (ii << 8);
    int jrow = f >> 5, kq = f & 31;
    float4 wv = ((const float4*)W)[f];
    float* wd = Wt + jrow;
    wd[(4 * kq + 0) * 132] = wv.x;
    wd[(4 * kq + 1) * 132] = wv.y;
    wd[(4 * kq + 2) * 132] = wv.z;
    wd[(4 * kq + 3) * 132] = wv.w;
  }
  const size_t R0 = (size_t)blockIdx.x << 5;   // 32 rows per block
  const float4* xg = (const float4*)(x + (R0 << 7));
  #pragma unroll
  for (int ii = 0; ii < 4; ++ii) {
    int f = tid + (ii << 8);
    int r = f >> 5, kq = f & 31;
    *(float4*)(xs + r * 132 + (kq << 2)) = xg[f];
  }
  __syncthreads();

  const int tr = tid >> 4, tc = tid & 15;
  const int r0 = tr << 1, j0 = tc << 3;
  float a0[8], a1[8];
  #pragma unroll
  for (int c = 0; c < 8; ++c) { a0[c] = 0.f; a1[c] = 0.f; }
  const float* xr0 = xs + r0 * 132;
  const float* xr1 = xs + (r0 + 1) * 132;
  const float* wc = Wt + j0;
  for (int k = 0; k < 128; k += 4) {
    float4 xa = *(const float4*)(xr0 + k);
    float4 xb = *(const float4*)(xr1 + k);
    #pragma unroll
    for (int s = 0; s < 4; ++s) {
      float4 w0 = *(const float4*)(wc + (k + s) * 132);
      float4 w1 = *(const float4*)(wc + (k + s) * 132 + 4);
      float xav = s == 0 ? xa.x : s == 1 ? xa.y : s == 2 ? xa.z : xa.w;
      float xbv = s == 0 ? xb.x : s == 1 ? xb.y : s == 2 ? xb.z : xb.w;
      a0[0] = fmaf(xav, w0.x, a0[0]); a0[1] = fmaf(xav, w0.y, a0[1]);
      a0[2] = fmaf(xav, w0.z, a0[2]); a0[3] = fmaf(xav, w0.w, a0[3]);
      a0[4] = fmaf(xav, w1.x, a0[4]); a0[5] = fmaf(xav, w1.y, a0[5]);
      a0[6] = fmaf(xav, w1.z, a0[6]); a0[7] = fmaf(xav, w1.w, a0[7]);
      a1[0] = fmaf(xbv, w0.x, a1[0]); a1[1] = fmaf(xbv, w0.y, a1[1]);
      a1[2] = fmaf(xbv, w0.z, a1[2]); a1[3] = fmaf(xbv, w0.w, a1[3]);
      a1[4] = fmaf(xbv, w1.x, a1[4]); a1[5] = fmaf(xbv, w1.y, a1[5]);
      a1[6] = fmaf(xbv, w1.z, a1[6]); a1[7] = fmaf(xbv, w1.w, a1[7]);
    }
  }
  float4 pb0 = *(const float4*)(pb + j0);
  float4 pb1 = *(const float4*)(pb + j0 + 4);
  a0[0] += pb0.x; a0[1] += pb0.y; a0[2] += pb0.z; a0[3] += pb0.w;
  a0[4] += pb1.x; a0[5] += pb1.y; a0[6] += pb1.z; a0[7] += pb1.w;
  a1[0] += pb0.x; a1[1] += pb0.y; a1[2] += pb0.z; a1[3] += pb0.w;
  a1[4] += pb1.x; a1[5] += pb1.y; a1[6] += pb1.z; a1[7] += pb1.w;
  float s0 = 0, q0 = 0, s1 = 0, q1 = 0;
  #pragma unroll
  for (int c = 0; c < 8; ++c) {
    s0 += a0[c]; q0 = fmaf(a0[c], a0[c], q0);
    s1 += a1[c]; q1 = fmaf(a1[c], a1[c], q1);
  }
  #pragma unroll
  for (int m = 1; m < 16; m <<= 1) {
    s0 += __shfl_xor(s0, m, 64); q0 += __shfl_xor(q0, m, 64);
    s1 += __shfl_xor(s1, m, 64); q1 += __shfl_xor(q1, m, 64);
  }
  float mu0 = s0 * (1.f / 128.f), mu1 = s1 * (1.f / 128.f);
  float rs0 = rsqrtf(fmaf(-mu0, mu0, q0 * (1.f / 128.f)) + 1e-5f);
  float rs1 = rsqrtf(fmaf(-mu1, mu1, q1 * (1.f / 128.f)) + 1e-5f);
  float4 g0 = *(const float4*)(lg + j0), g1 = *(const float4*)(lg + j0 + 4);
  float4 b0 = *(const float4*)(lb + j0), b1 = *(const float4*)(lb + j0 + 4);
  float n0[8], n1[8];
  const float* gv = (const float*)&g0; const float* bv = (const float*)&b0;
  #pragma unroll
  for (int c = 0; c < 4; ++c) {
    n0[c] = fmaf((a0[c] - mu0) * rs0, gv[c], bv[c]);
    n1[c] = fmaf((a1[c] - mu1) * rs1, gv[c], bv[c]);
  }
  const float* gv1 = (const float*)&g1; const float* bv1 = (const float*)&b1;
  #pragma unroll
  for (int c = 0; c < 4; ++c) {
    n0[4 + c] = fmaf((a0[4 + c] - mu0) * rs0, gv1[c], bv1[c]);
    n1[4 + c] = fmaf((a1[4 + c] - mu1) * rs1, gv1[c], bv1[c]);
  }
  uint4 o0, o1;
  o0.x = pk2(n0[0], n0[1]); o0.y = pk2(n0[2], n0[3]);
  o0.z = pk2(n0[4], n0[5]); o0.w = pk2(n0[6], n0[7]);
  o1.x = pk2(n1[0], n1[1]); o1.y = pk2(n1[2], n1[3]);
  o1.z = pk2(n1[4], n1[5]); o1.w = pk2(n1[6], n1[7]);
  hout[(R0 + r0) * 16 + tc] = o0;
  hout[(R0 + r0 + 1) * 16 + tc] = o1;
}

// ---------------- stage B: sensory terms — R8 form (global params), DPP reduce ----------------
__global__ __launch_bounds__(1024, 4) void sensory_kernel(
    const float* __restrict__ C2, const float* __restrict__ A2,
    const float* __restrict__ WE,
    const uint4* __restrict__ hbf, unsigned* __restrict__ ndg)
{
  const int tid = threadIdx.x;
  const int lane = tid & 63, wv = tid >> 6;
  const int iq = lane & 7, jj = lane >> 3;
  const int j = wv * 8 + jj;

  float c2s[16], a2s[16], wes[16];
  const int pbase = j * 128 + iq * 16;
  #pragma unroll
  for (int k = 0; k < 16; ++k) {
    c2s[k] = C2[pbase + k];
    a2s[k] = A2[pbase + k];
    wes[k] = WE[pbase + k];
  }

  const int p0 = blockIdx.x << 9;        // 512 pairs per block
  uint4 hc0 = hbf[((size_t)p0 << 4) + iq * 2];
  uint4 hc1 = hbf[((size_t)p0 << 4) + iq * 2 + 1];

  for (int q = 0; q < 512; ++q) {
    const int p = p0 + q;
    const int pn = p0 + (q + 1 < 512 ? q + 1 : q);
    uint4 hn0 = hbf[((size_t)pn << 4) + iq * 2];
    uint4 hn1 = hbf[((size_t)pn << 4) + iq * 2 + 1];

    float hv[16];
    hv[0] = bl16(hc0.x);  hv[1] = bh16(hc0.x);
    hv[2] = bl16(hc0.y);  hv[3] = bh16(hc0.y);
    hv[4] = bl16(hc0.z);  hv[5] = bh16(hc0.z);
    hv[6] = bl16(hc0.w);  hv[7] = bh16(hc0.w);
    hv[8] = bl16(hc1.x);  hv[9] = bh16(hc1.x);
    hv[10] = bl16(hc1.y); hv[11] = bh16(hc1.y);
    hv[12] = bl16(hc1.z); hv[13] = bh16(hc1.z);
    hv[14] = bl16(hc1.w); hv[15] = bh16(hc1.w);

    float an = 0.f, ad = 0.f;
    #pragma unroll
    for (int k = 0; k < 16; ++k) {
      float t = fmaf(-a2s[k], hv[k], c2s[k]);
      float e = __builtin_amdgcn_exp2f(t);
      float r = __builtin_amdgcn_rcpf(1.0f + e);
      an = fmaf(wes[k], r, an);
      ad = fmaf(fabsf(wes[k]), r, ad);
    }

    an = red8(an);
    ad = red8(ad);
    if (iq == 0) ndg[((size_t)p << 7) + j] = pk2(an, ad);
    hc0 = hn0; hc1 = hn1;
  }
}

// ---------------- stage C: LTC scan — params in LDS (swizzled image), we in regs ----------------
__global__ __launch_bounds__(1024, 4) void ltc_scan(
    const float2* __restrict__ Pimg, const float* __restrict__ WEr,
    const float* __restrict__ vecs, const unsigned* __restrict__ ndg,
    const float* __restrict__ ow, const float* __restrict__ ob,
    const float* __restrict__ lng, const float* __restrict__ lnb,
    const float* __restrict__ hW, const float* __restrict__ hb,
    float* __restrict__ out)
{
  extern __shared__ char smem[];
  char* Plds  = smem;                          // 131072 B swizzled {c2,a2} image
  float* vbuf0 = (float*)(smem + 131072);      // 288 f (stride-36 x 8)
  float* vbuf1 = vbuf0 + 288;                  // 288 f
  float* ov    = vbuf1 + 288;                  // 128
  float* lnv   = ov + 128;                     // 128
  float* mv    = lnv + 128;                    // 2

  const int tid = threadIdx.x;
  const int lane = tid & 63, wv = tid >> 6;
  const int iq = lane & 7, jj0 = lane >> 3;
  const int j = wv * 8 + jj0;
  const int jj = j & 7;                        // == jj0 & 7 == lane>>3 & 7
  const int b = blockIdx.x;
  const int vpos_j = ((j >> 4) * 36) + (j & 15);

  // one-time param image copy: 128 KB, float4 x 8 per thread
  {
    const float4* img4 = (const float4*)Pimg;
    float4* dst4 = (float4*)Plds;
    #pragma unroll
    for (int it = 0; it < 8; ++it) {
      int idx = tid + (it << 10);
      dst4[idx] = img4[idx];
    }
  }
  // we in registers: 16 consecutive floats
  float4 wq[4];
  {
    const float4* wp = (const float4*)(WEr + j * 128 + iq * 16);
    wq[0] = wp[0]; wq[1] = wp[1]; wq[2] = wp[2]; wq[3] = wp[3];
  }
  const float cmtj = vecs[j];
  const float gdj  = vecs[128 + j];
  const float gnj  = vecs[256 + j];
  const float cgd  = cmtj + gdj + 1e-8f;
  float vj = 0.f;
  if (tid < 128) vbuf0[((tid >> 4) * 36) + (tid & 15)] = 0.f;
  __syncthreads();

  const char* pbase = Plds + j * 1024 + iq * 128;   // this thread's param row
  const size_t ndbase = ((size_t)b << 17) + j;
  unsigned ndc = ndg[ndbase];
  for (int t = 0; t < 1024; ++t) {
    const int tn = (t + 1 < 1024) ? t + 1 : 1023;
    unsigned ndn = ndg[ndbase + ((size_t)tn << 7)];   // prefetch stays in flight
    const float snum = bl16(ndc), sden = bh16(ndc);
    #pragma unroll
    for (int u = 0; u < 4; ++u) {
      const float* vc = (u & 1 ? vbuf1 : vbuf0) + iq * 36;
      float an = 0.f, ad = 0.f;
      #pragma unroll
      for (int cq = 0; cq < 4; ++cq) {
        float4 vv = *(const float4*)(vc + 4 * cq);
        float4 pA = *(const float4*)(pbase + (((2 * cq)     ^ jj) << 4));
        float4 pB = *(const float4*)(pbase + (((2 * cq + 1) ^ jj) << 4));
        float w0 = cq == 0 ? wq[0].x : cq == 1 ? wq[1].x : cq == 2 ? wq[2].x : wq[3].x;
        float w1 = cq == 0 ? wq[0].y : cq == 1 ? wq[1].y : cq == 2 ? wq[2].y : wq[3].y;
        float w2 = cq == 0 ? wq[0].z : cq == 1 ? wq[1].z : cq == 2 ? wq[2].z : wq[3].z;
        float w3 = cq == 0 ? wq[0].w : cq == 1 ? wq[1].w : cq == 2 ? wq[2].w : wq[3].w;
        float r0 = __builtin_amdgcn_rcpf(1.0f + __builtin_amdgcn_exp2f(fmaf(-pA.y, vv.x, pA.x)));
        float r1 = __builtin_amdgcn_rcpf(1.0f + __builtin_amdgcn_exp2f(fmaf(-pA.w, vv.y, pA.z)));
        float r2 = __builtin_amdgcn_rcpf(1.0f + __builtin_amdgcn_exp2f(fmaf(-pB.y, vv.z, pB.x)));
        float r3 = __builtin_amdgcn_rcpf(1.0f + __builtin_amdgcn_exp2f(fmaf(-pB.w, vv.w, pB.z)));
        an = fmaf(w0, r0, an); ad = fmaf(fabsf(w0), r0, ad);
        an = fmaf(w1, r1, an); ad = fmaf(fabsf(w1), r1, ad);
        an = fmaf(w2, r2, an); ad = fmaf(fabsf(w2), r2, ad);
        an = fmaf(w3, r3, an); ad = fmaf(fabsf(w3), r3, ad);
      }
      an = red8(an);
      ad = red8(ad);
      float num = an + snum;
      float den = ad + sden;
      float vnew = (fmaf(cmtj, vj, gnj) + num) *
                   __builtin_amdgcn_rcpf(cgd + den);
      if (iq == 0) (u & 1 ? vbuf0 : vbuf1)[vpos_j] = vnew;
      vj = vnew;
      lds_barrier();               // LDS-visibility only; no vmcnt drain
    }
    ndc = ndn;
  }

  // epilogue: out affine -> layernorm -> head matmul (final v is in vbuf0)
  __syncthreads();
  if (tid < 128)
    ov[tid] = fmaf(vbuf0[((tid >> 4) * 36) + (tid & 15)], ow[tid], ob[tid]);
  __syncthreads();
  if (tid < 64) {
    float a = ov[tid], c = ov[tid + 64];
    float s = a + c, s2 = fmaf(a, a, c * c);
    #pragma unroll
    for (int m = 1; m < 64; m <<= 1) {
      s += __shfl_xor(s, m, 64);
      s2 += __shfl_xor(s2, m, 64);
    }
    if (tid == 0) {
      float mean = s * (1.f / 128.f);
      float var = s2 * (1.f / 128.f) - mean * mean;
      mv[0] = mean;
      mv[1] = rsqrtf(var + 1e-5f);
    }
  }
  __syncthreads();
  if (tid < 128) lnv[tid] = fmaf((ov[tid] - mv[0]) * mv[1], lng[tid], lnb[tid]);
  __syncthreads();
  if (tid < 15) {
    float acc = hb[tid];
    const float* wr = hW + tid * 128;
    #pragma unroll
    for (int k = 0; k < 128; k += 4) {
      float4 wvv = *(const float4*)(wr + k);
      acc = fmaf(wvv.x, lnv[k], acc);
      acc = fmaf(wvv.y, lnv[k + 1], acc);
      acc = fmaf(wvv.z, lnv[k + 2], acc);
      acc = fmaf(wvv.w, lnv[k + 3], acc);
    }
    out[b * 15 + tid] = acc;
  }
}

// ---------------- launch ----------------
extern "C" void kernel_launch(void* const* d_in, const int* in_sizes, int n_in,
                              void* d_out, int out_size, void* d_ws, size_t ws_size,
                              hipStream_t stream) {
  const float* x      = (const float*)d_in[0];
  const float* pre_W  = (const float*)d_in[1];
  const float* pre_b  = (const float*)d_in[2];
  const float* plg    = (const float*)d_in[3];
  const float* plb    = (const float*)d_in[4];
  const float* gleak  = (const float*)d_in[5];
  const float* vleak  = (const float*)d_in[6];
  const float* cm     = (const float*)d_in[7];
  const float* sigma  = (const float*)d_in[8];
  const float* mu     = (const float*)d_in[9];
  const float* w      = (const float*)d_in[10];
  const float* erev   = (const float*)d_in[11];
  const float* ss     = (const float*)d_in[12];
  const float* smu    = (const float*)d_in[13];
  const float* sw     = (const float*)d_in[14];
  const float* serev  = (const float*)d_in[15];
  const float* iw     = (const float*)d_in[16];
  const float* ib     = (const float*)d_in[17];
  const float* ow     = (const float*)d_in[18];
  const float* ob     = (const float*)d_in[19];
  const float* lng    = (const float*)d_in[20];
  const float* lnb    = (const float*)d_in[21];
  const float* hW     = (const float*)d_in[22];
  const float* hb     = (const float*)d_in[23];
  float* out = (float*)d_out;

  char* ws = (char*)d_ws;
  float2* Pimg = (float2*)(ws + 0);            // 128 KB swizzled {c2,a2}
  float* WEr   = (float*)(ws + 131072);        // 64 KB
  float* C2s   = (float*)(ws + 196608);
  float* A2s   = (float*)(ws + 262144);
  float* WEs   = (float*)(ws + 327680);
  float* vecs  = (float*)(ws + 393216);        // 1.5 KB
  uint4* hbf   = (uint4*)(ws + 1048576);                 // 32 MB (bf16 h_ln)
  unsigned* ndg = (unsigned*)(ws + 1048576 + 33554432);  // 64 MB (bf16 num|den)

  prep_kernel<<<129, 256, 0, stream>>>(sigma, mu, w, erev, ss, smu, sw, serev,
                                       iw, ib, gleak, vleak, cm,
                                       Pimg, WEr, C2s, A2s, WEs, vecs);
  stage_a<<<4096, 256, 84480, stream>>>(x, pre_W, pre_b, plg, plb, hbf);
  sensory_kernel<<<256, 1024, 0, stream>>>(C2s, A2s, WEs, hbf, ndg);
  ltc_scan<<<128, 1024, 134480, stream>>>(Pimg, WEr, vecs, ndg,
                                          ow, ob, lng, lnb, hW, hb, out);
}

// Round 12
// 4351.735 us; speedup vs baseline: 1.1942x; 1.1942x over previous
//
#include <hip/hip_runtime.h>

#define LOG2E 1.4426950408889634f

typedef float f32x2 __attribute__((ext_vector_type(2)));

__device__ __forceinline__ unsigned short f2bf(float f) {
  unsigned u = __float_as_uint(f);
  u += 0x7FFFu + ((u >> 16) & 1u);            // round-to-nearest-even
  return (unsigned short)(u >> 16);
}
__device__ __forceinline__ unsigned pk2(float a, float b) {
  return (unsigned)f2bf(a) | ((unsigned)f2bf(b) << 16);
}
__device__ __forceinline__ float bl16(unsigned u) { return __uint_as_float(u << 16); }
__device__ __forceinline__ float bh16(unsigned u) { return __uint_as_float(u & 0xFFFF0000u); }

// LDS-visibility barrier WITHOUT the vmcnt(0) drain __syncthreads would emit:
// the ndg prefetch stays in flight across unfold boundaries.
__device__ __forceinline__ void lds_barrier() {
  asm volatile("s_waitcnt lgkmcnt(0)" ::: "memory");
  __builtin_amdgcn_s_barrier();
}

// DPP cross-lane adds (VALU pipe): reduce over 8 consecutive lanes.
__device__ __forceinline__ float dpp_xor1_add(float x) {
  return x + __int_as_float(__builtin_amdgcn_update_dpp(
      0, __float_as_int(x), 0xB1, 0xF, 0xF, true));
}
__device__ __forceinline__ float dpp_xor2_add(float x) {
  return x + __int_as_float(__builtin_amdgcn_update_dpp(
      0, __float_as_int(x), 0x4E, 0xF, 0xF, true));
}
__device__ __forceinline__ float dpp_xor7_add(float x) {
  return x + __int_as_float(__builtin_amdgcn_update_dpp(
      0, __float_as_int(x), 0x141, 0xF, 0xF, true));
}
__device__ __forceinline__ float red8(float x) {
  x = dpp_xor1_add(x);
  x = dpp_xor2_add(x);
  x = dpp_xor7_add(x);
  return x;
}

// packed sigmoid-weighted accumulate (R4 form; compiler scalarizes f32x2 — known-good)
__device__ __forceinline__ void sigacc2(f32x2 c2, f32x2 a2, f32x2 we, f32x2 aw,
                                        f32x2 vi, f32x2& an, f32x2& ad) {
  f32x2 t = c2 - a2 * vi;
  f32x2 e;
  e.x = __builtin_amdgcn_exp2f(t.x);
  e.y = __builtin_amdgcn_exp2f(t.y);
  f32x2 s = e + 1.0f;
  f32x2 r;
  r.x = __builtin_amdgcn_rcpf(s.x);
  r.y = __builtin_amdgcn_rcpf(s.y);
  an += we * r;
  ad += aw * r;
}

// ---------------- prep: fold constants, softplus, emit SoA [j][i] f32 ----------------
__global__ __launch_bounds__(256) void prep_kernel(
    const float* __restrict__ sigma, const float* __restrict__ mu,
    const float* __restrict__ w,     const float* __restrict__ erev,
    const float* __restrict__ ss,    const float* __restrict__ smu,
    const float* __restrict__ sw,    const float* __restrict__ serev,
    const float* __restrict__ iw,    const float* __restrict__ ib,
    const float* __restrict__ gleak, const float* __restrict__ vleak,
    const float* __restrict__ cm,
    float* __restrict__ C2r, float* __restrict__ A2r,
    float* __restrict__ WEr, float* __restrict__ AWr,
    float* __restrict__ C2s, float* __restrict__ A2s,
    float* __restrict__ WEs, float* __restrict__ AWs,
    float* __restrict__ vecs)
{
  int gid = blockIdx.x * 256 + threadIdx.x;
  if (gid < 16384) {
    int i = gid >> 7, j = gid & 127;
    int idx = j * 128 + i;                    // transposed SoA [j][i]
    float a2 = sigma[gid] * LOG2E;
    float c2 = a2 * mu[gid];
    float sp = log1pf(expf(w[gid]));          // softplus(w) > 0
    float we = sp * erev[gid];                // erev = +-1
    C2r[idx] = c2; A2r[idx] = a2; WEr[idx] = we; AWr[idx] = sp;
  } else if (gid < 32768) {
    int e = gid - 16384;
    int i = e >> 7, j = e & 127;
    int idx = j * 128 + i;
    float a2 = ss[e] * iw[i] * LOG2E;         // fold input_w
    float c2 = ss[e] * (smu[e] - ib[i]) * LOG2E; // fold input_b
    float sp = log1pf(expf(sw[e]));
    float we = sp * serev[e];
    C2s[idx] = c2; A2s[idx] = a2; WEs[idx] = we; AWs[idx] = sp;
  } else if (gid < 32896) {
    int jj = gid - 32768;
    float gp = log1pf(expf(gleak[jj]));
    vecs[jj]       = log1pf(expf(cm[jj])) * 4.0f; // cm_t = softplus(cm)*ODE_UNFOLDS
    vecs[128 + jj] = gp;                          // gleak_p
    vecs[256 + jj] = gp * vleak[jj];              // gleak_p * vleak
  }
}

// ---------------- stage A: h = LN(x @ W^T + b), write bf16 (unchanged, known-good) ----------------
__global__ __launch_bounds__(256) void stage_a(
    const float* __restrict__ x, const float* __restrict__ W,
    const float* __restrict__ pb, const float* __restrict__ lg,
    const float* __restrict__ lb, uint4* __restrict__ hout)
{
  extern __shared__ char smem[];
  float* Wt = (float*)smem;            // [128][132] transposed W (k-major), padded
  float* xs = Wt + 128 * 132;          // [32][132]
  const int tid = threadIdx.x;

  #pragma unroll
  for (int ii = 0; ii < 16; ++ii) {
    int f = tid + (ii << 8);
    int jrow = f >> 5, kq = f & 31;
    float4 wv = ((const float4*)W)[f];
    float* wd = Wt + jrow;
    wd[(4 * kq + 0) * 132] = wv.x;
    wd[(4 * kq + 1) * 132] = wv.y;
    wd[(4 * kq + 2) * 132] = wv.z;
    wd[(4 * kq + 3) * 132] = wv.w;
  }
  const size_t R0 = (size_t)blockIdx.x << 5;   // 32 rows per block
  const float4* xg = (const float4*)(x + (R0 << 7));
  #pragma unroll
  for (int ii = 0; ii < 4; ++ii) {
    int f = tid + (ii << 8);
    int r = f >> 5, kq = f & 31;
    *(float4*)(xs + r * 132 + (kq << 2)) = xg[f];
  }
  __syncthreads();

  const int tr = tid >> 4, tc = tid & 15;
  const int r0 = tr << 1, j0 = tc << 3;
  float a0[8], a1[8];
  #pragma unroll
  for (int c = 0; c < 8; ++c) { a0[c] = 0.f; a1[c] = 0.f; }
  const float* xr0 = xs + r0 * 132;
  const float* xr1 = xs + (r0 + 1) * 132;
  const float* wc = Wt + j0;
  for (int k = 0; k < 128; k += 4) {
    float4 xa = *(const float4*)(xr0 + k);
    float4 xb = *(const float4*)(xr1 + k);
    #pragma unroll
    for (int s = 0; s < 4; ++s) {
      float4 w0 = *(const float4*)(wc + (k + s) * 132);
      float4 w1 = *(const float4*)(wc + (k + s) * 132 + 4);
      float xav = s == 0 ? xa.x : s == 1 ? xa.y : s == 2 ? xa.z : xa.w;
      float xbv = s == 0 ? xb.x : s == 1 ? xb.y : s == 2 ? xb.z : xb.w;
      a0[0] = fmaf(xav, w0.x, a0[0]); a0[1] = fmaf(xav, w0.y, a0[1]);
      a0[2] = fmaf(xav, w0.z, a0[2]); a0[3] = fmaf(xav, w0.w, a0[3]);
      a0[4] = fmaf(xav, w1.x, a0[4]); a0[5] = fmaf(xav, w1.y, a0[5]);
      a0[6] = fmaf(xav, w1.z, a0[6]); a0[7] = fmaf(xav, w1.w, a0[7]);
      a1[0] = fmaf(xbv, w0.x, a1[0]); a1[1] = fmaf(xbv, w0.y, a1[1]);
      a1[2] = fmaf(xbv, w0.z, a1[2]); a1[3] = fmaf(xbv, w0.w, a1[3]);
      a1[4] = fmaf(xbv, w1.x, a1[4]); a1[5] = fmaf(xbv, w1.y, a1[5]);
      a1[6] = fmaf(xbv, w1.z, a1[6]); a1[7] = fmaf(xbv, w1.w, a1[7]);
    }
  }
  float4 pb0 = *(const float4*)(pb + j0);
  float4 pb1 = *(const float4*)(pb + j0 + 4);
  a0[0] += pb0.x; a0[1] += pb0.y; a0[2] += pb0.z; a0[3] += pb0.w;
  a0[4] += pb1.x; a0[5] += pb1.y; a0[6] += pb1.z; a0[7] += pb1.w;
  a1[0] += pb0.x; a1[1] += pb0.y; a1[2] += pb0.z; a1[3] += pb0.w;
  a1[4] += pb1.x; a1[5] += pb1.y; a1[6] += pb1.z; a1[7] += pb1.w;
  float s0 = 0, q0 = 0, s1 = 0, q1 = 0;
  #pragma unroll
  for (int c = 0; c < 8; ++c) {
    s0 += a0[c]; q0 = fmaf(a0[c], a0[c], q0);
    s1 += a1[c]; q1 = fmaf(a1[c], a1[c], q1);
  }
  #pragma unroll
  for (int m = 1; m < 16; m <<= 1) {
    s0 += __shfl_xor(s0, m, 64); q0 += __shfl_xor(q0, m, 64);
    s1 += __shfl_xor(s1, m, 64); q1 += __shfl_xor(q1, m, 64);
  }
  float mu0 = s0 * (1.f / 128.f), mu1 = s1 * (1.f / 128.f);
  float rs0 = rsqrtf(fmaf(-mu0, mu0, q0 * (1.f / 128.f)) + 1e-5f);
  float rs1 = rsqrtf(fmaf(-mu1, mu1, q1 * (1.f / 128.f)) + 1e-5f);
  float4 g0 = *(const float4*)(lg + j0), g1 = *(const float4*)(lg + j0 + 4);
  float4 b0 = *(const float4*)(lb + j0), b1 = *(const float4*)(lb + j0 + 4);
  float n0[8], n1[8];
  const float* gv = (const float*)&g0; const float* bv = (const float*)&b0;
  #pragma unroll
  for (int c = 0; c < 4; ++c) {
    n0[c] = fmaf((a0[c] - mu0) * rs0, gv[c], bv[c]);
    n1[c] = fmaf((a1[c] - mu1) * rs1, gv[c], bv[c]);
  }
  const float* gv1 = (const float*)&g1; const float* bv1 = (const float*)&b1;
  #pragma unroll
  for (int c = 0; c < 4; ++c) {
    n0[4 + c] = fmaf((a0[4 + c] - mu0) * rs0, gv1[c], bv1[c]);
    n1[4 + c] = fmaf((a1[4 + c] - mu1) * rs1, gv1[c], bv1[c]);
  }
  uint4 o0, o1;
  o0.x = pk2(n0[0], n0[1]); o0.y = pk2(n0[2], n0[3]);
  o0.z = pk2(n0[4], n0[5]); o0.w = pk2(n0[6], n0[7]);
  o1.x = pk2(n1[0], n1[1]); o1.y = pk2(n1[2], n1[3]);
  o1.z = pk2(n1[4], n1[5]); o1.w = pk2(n1[6], n1[7]);
  hout[(R0 + r0) * 16 + tc] = o0;
  hout[(R0 + r0 + 1) * 16 + tc] = o1;
}

// ---------------- stage B: sensory terms — R4 form (f32x2 reg params, DPP reduce) ----------------
__global__ __launch_bounds__(1024, 4) void sensory_kernel(
    const float* __restrict__ C2, const float* __restrict__ A2,
    const float* __restrict__ WE, const float* __restrict__ AW,
    const uint4* __restrict__ hbf, unsigned* __restrict__ ndg)
{
  const int tid = threadIdx.x;
  const int lane = tid & 63, wv = tid >> 6;
  const int iq = lane & 7, jj = lane >> 3;
  const int j = wv * 8 + jj;

  f32x2 c22[8], a22[8], we2[8], aw2[8];
  const int pbase = j * 128 + iq * 16;
  #pragma unroll
  for (int p = 0; p < 8; ++p) {
    c22[p] = *(const f32x2*)(C2 + pbase + 2 * p);
    a22[p] = *(const f32x2*)(A2 + pbase + 2 * p);
    we2[p] = *(const f32x2*)(WE + pbase + 2 * p);
    aw2[p] = *(const f32x2*)(AW + pbase + 2 * p);
  }

  const int p0 = blockIdx.x << 9;        // 512 pairs per block
  uint4 hc0 = hbf[((size_t)p0 << 4) + iq * 2];
  uint4 hc1 = hbf[((size_t)p0 << 4) + iq * 2 + 1];

  for (int q = 0; q < 512; ++q) {
    const int p = p0 + q;
    const int pn = p0 + (q + 1 < 512 ? q + 1 : q);
    uint4 hn0 = hbf[((size_t)pn << 4) + iq * 2];
    uint4 hn1 = hbf[((size_t)pn << 4) + iq * 2 + 1];

    f32x2 hv[8];
    hv[0].x = bl16(hc0.x); hv[0].y = bh16(hc0.x);
    hv[1].x = bl16(hc0.y); hv[1].y = bh16(hc0.y);
    hv[2].x = bl16(hc0.z); hv[2].y = bh16(hc0.z);
    hv[3].x = bl16(hc0.w); hv[3].y = bh16(hc0.w);
    hv[4].x = bl16(hc1.x); hv[4].y = bh16(hc1.x);
    hv[5].x = bl16(hc1.y); hv[5].y = bh16(hc1.y);
    hv[6].x = bl16(hc1.z); hv[6].y = bh16(hc1.z);
    hv[7].x = bl16(hc1.w); hv[7].y = bh16(hc1.w);

    f32x2 an2 = {0.f, 0.f}, ad2 = {0.f, 0.f};
    #pragma unroll
    for (int p8 = 0; p8 < 8; ++p8)
      sigacc2(c22[p8], a22[p8], we2[p8], aw2[p8], hv[p8], an2, ad2);

    float an = red8(an2.x + an2.y);
    float ad = red8(ad2.x + ad2.y);
    if (iq == 0) ndg[((size_t)p << 7) + j] = pk2(an, ad);
    hc0 = hn0; hc1 = hn1;
  }
}

// ---------------- stage C: sequential LTC scan — R4 verbatim + drain-free barriers ----------------
__global__ __launch_bounds__(1024, 4) void ltc_scan(
    const float* __restrict__ C2, const float* __restrict__ A2,
    const float* __restrict__ WE, const float* __restrict__ AW,
    const float* __restrict__ vecs, const unsigned* __restrict__ ndg,
    const float* __restrict__ ow, const float* __restrict__ ob,
    const float* __restrict__ lng, const float* __restrict__ lnb,
    const float* __restrict__ hW, const float* __restrict__ hb,
    float* __restrict__ out)
{
  __shared__ float vbuf[2][8 * 36];
  __shared__ float ov[128], lnv[128], mv[2];

  const int tid = threadIdx.x;
  const int lane = tid & 63, wv = tid >> 6;
  const int iq = lane & 7, jj = lane >> 3;
  const int j = wv * 8 + jj;
  const int b = blockIdx.x;
  const int vpos_j = ((j >> 4) * 36) + (j & 15);

  f32x2 c22[8], a22[8], we2[8], aw2[8];
  const int pbase = j * 128 + iq * 16;
  #pragma unroll
  for (int p = 0; p < 8; ++p) {
    c22[p] = *(const f32x2*)(C2 + pbase + 2 * p);
    a22[p] = *(const f32x2*)(A2 + pbase + 2 * p);
    we2[p] = *(const f32x2*)(WE + pbase + 2 * p);
    aw2[p] = *(const f32x2*)(AW + pbase + 2 * p);
  }
  const float cmtj = vecs[j];
  const float gdj  = vecs[128 + j];
  const float gnj  = vecs[256 + j];
  float vj = 0.f;
  if (tid < 128) vbuf[0][((tid >> 4) * 36) + (tid & 15)] = 0.f;
  __syncthreads();

  const size_t ndbase = ((size_t)b << 17) + j;   // b*1024*128 + j
  unsigned ndc = ndg[ndbase];                    // t = 0 sensory terms
  for (int t = 0; t < 1024; ++t) {
    const int tn = (t + 1 < 1024) ? t + 1 : 1023;
    unsigned ndn = ndg[ndbase + ((size_t)tn << 7)];   // prefetch next t (stays in flight now)
    const float snum = bl16(ndc), sden = bh16(ndc);
    #pragma unroll
    for (int u = 0; u < 4; ++u) {
      const float* vc = vbuf[u & 1] + iq * 36;
      f32x2 an2 = {0.f, 0.f}, ad2 = {0.f, 0.f};
      #pragma unroll
      for (int c = 0; c < 4; ++c) {
        float4 vv = *(const float4*)(vc + 4 * c);
        f32x2 vA; vA.x = vv.x; vA.y = vv.y;
        f32x2 vB; vB.x = vv.z; vB.y = vv.w;
        sigacc2(c22[2 * c],     a22[2 * c],     we2[2 * c],     aw2[2 * c],     vA, an2, ad2);
        sigacc2(c22[2 * c + 1], a22[2 * c + 1], we2[2 * c + 1], aw2[2 * c + 1], vB, an2, ad2);
      }
      float an = red8(an2.x + an2.y);
      float ad = red8(ad2.x + ad2.y);
      // all lanes compute vnew for their j (identical across iq dups) -> vj stays in reg
      float num = an + snum;
      float den = ad + sden;
      float vnew = (fmaf(cmtj, vj, gnj) + num) *
                   __builtin_amdgcn_rcpf(cmtj + gdj + den + 1e-8f);
      if (iq == 0) vbuf[(u & 1) ^ 1][vpos_j] = vnew;
      vj = vnew;
      lds_barrier();               // LDS-visibility only; ndg prefetch not drained
    }
    ndc = ndn;
  }

  // epilogue: out affine -> layernorm -> head matmul (final v is in vbuf[0], padded layout)
  __syncthreads();
  if (tid < 128)
    ov[tid] = fmaf(vbuf[0][((tid >> 4) * 36) + (tid & 15)], ow[tid], ob[tid]);
  __syncthreads();
  if (tid < 64) {
    float a = ov[tid], c = ov[tid + 64];
    float s = a + c, s2 = fmaf(a, a, c * c);
    #pragma unroll
    for (int m = 1; m < 64; m <<= 1) {
      s += __shfl_xor(s, m, 64);
      s2 += __shfl_xor(s2, m, 64);
    }
    if (tid == 0) {
      float mean = s * (1.f / 128.f);
      float var = s2 * (1.f / 128.f) - mean * mean;
      mv[0] = mean;
      mv[1] = rsqrtf(var + 1e-5f);
    }
  }
  __syncthreads();
  if (tid < 128) lnv[tid] = fmaf((ov[tid] - mv[0]) * mv[1], lng[tid], lnb[tid]);
  __syncthreads();
  if (tid < 15) {
    float acc = hb[tid];
    const float* wr = hW + tid * 128;
    #pragma unroll
    for (int k = 0; k < 128; k += 4) {
      float4 wvv = *(const float4*)(wr + k);
      acc = fmaf(wvv.x, lnv[k], acc);
      acc = fmaf(wvv.y, lnv[k + 1], acc);
      acc = fmaf(wvv.z, lnv[k + 2], acc);
      acc = fmaf(wvv.w, lnv[k + 3], acc);
    }
    out[b * 15 + tid] = acc;
  }
}

// ---------------- launch ----------------
extern "C" void kernel_launch(void* const* d_in, const int* in_sizes, int n_in,
                              void* d_out, int out_size, void* d_ws, size_t ws_size,
                              hipStream_t stream) {
  const float* x      = (const float*)d_in[0];
  const float* pre_W  = (const float*)d_in[1];
  const float* pre_b  = (const float*)d_in[2];
  const float* plg    = (const float*)d_in[3];
  const float* plb    = (const float*)d_in[4];
  const float* gleak  = (const float*)d_in[5];
  const float* vleak  = (const float*)d_in[6];
  const float* cm     = (const float*)d_in[7];
  const float* sigma  = (const float*)d_in[8];
  const float* mu     = (const float*)d_in[9];
  const float* w      = (const float*)d_in[10];
  const float* erev   = (const float*)d_in[11];
  const float* ss     = (const float*)d_in[12];
  const float* smu    = (const float*)d_in[13];
  const float* sw     = (const float*)d_in[14];
  const float* serev  = (const float*)d_in[15];
  const float* iw     = (const float*)d_in[16];
  const float* ib     = (const float*)d_in[17];
  const float* ow     = (const float*)d_in[18];
  const float* ob     = (const float*)d_in[19];
  const float* lng    = (const float*)d_in[20];
  const float* lnb    = (const float*)d_in[21];
  const float* hW     = (const float*)d_in[22];
  const float* hb     = (const float*)d_in[23];
  float* out = (float*)d_out;

  char* ws = (char*)d_ws;
  float* C2r = (float*)(ws + 0 * 65536);
  float* A2r = (float*)(ws + 1 * 65536);
  float* WEr = (float*)(ws + 2 * 65536);
  float* AWr = (float*)(ws + 3 * 65536);
  float* C2s = (float*)(ws + 4 * 65536);
  float* A2s = (float*)(ws + 5 * 65536);
  float* WEs = (float*)(ws + 6 * 65536);
  float* AWs = (float*)(ws + 7 * 65536);
  float* vecs   = (float*)(ws + 8 * 65536);               // 1.5 KB
  uint4* hbf    = (uint4*)(ws + 1048576);                 // 32 MB (bf16 h_ln)
  unsigned* ndg = (unsigned*)(ws + 1048576 + 33554432);   // 64 MB (bf16 num|den)

  prep_kernel<<<129, 256, 0, stream>>>(sigma, mu, w, erev, ss, smu, sw, serev,
                                       iw, ib, gleak, vleak, cm,
                                       C2r, A2r, WEr, AWr, C2s, A2s, WEs, AWs, vecs);
  stage_a<<<4096, 256, 84480, stream>>>(x, pre_W, pre_b, plg, plb, hbf);
  sensory_kernel<<<256, 1024, 0, stream>>>(C2s, A2s, WEs, AWs, hbf, ndg);
  ltc_scan<<<128, 1024, 0, stream>>>(C2r, A2r, WEr, AWr, vecs, ndg,
                                     ow, ob, lng, lnb, hW, hb, out);
}